// Round 1
// baseline (5783.591 us; speedup 1.0000x reference)
//
#include <hip/hip_runtime.h>
#include <math.h>

#define N_M 100000
#define N_E 50000
#define FM 256
#define FE 64
#define H 128
#define NEDGE 1000000
#define NLBL 250000

// ---------------------------------------------------------------------------
// Generic tiled GEMM: C[M,128] = act( (A1 * (MEAN ? 1/max(cnt,1) : 1)) @ W1
//                                     [+ A2 @ W2]  + bias )
// TM=64 rows per block, 256 threads, each thread 8 rows x 4 cols.
// In-place safe when C == A1 (or A2): each output row depends only on the
// same input row, and all k-chunks are consumed before the epilogue writes.
// ---------------------------------------------------------------------------
template<int K, bool HAS_A2, bool RELU, bool MEAN>
__global__ __launch_bounds__(256)
void gemm_kernel(const float* __restrict__ A1,
                 const float* __restrict__ cnt,
                 const float* __restrict__ W1,
                 const float* __restrict__ A2,
                 const float* __restrict__ W2,
                 const float* __restrict__ bias,
                 float* __restrict__ C, int M)
{
    constexpr int TM = 64, KC = 32, N = 128;
    __shared__ float As[TM][KC + 1];
    __shared__ float Ws[KC][N];
    __shared__ float rs[TM];

    const int tid  = threadIdx.x;
    const int row0 = blockIdx.x * TM;
    const int c0   = (tid & 31) * 4;
    const int r0   = (tid >> 5) * 8;

    float acc[8][4];
    #pragma unroll
    for (int r = 0; r < 8; ++r) {
        acc[r][0] = 0.f; acc[r][1] = 0.f; acc[r][2] = 0.f; acc[r][3] = 0.f;
    }

    if (MEAN) {
        if (tid < TM) {
            int row = row0 + tid;
            float c = (row < M) ? cnt[row] : 1.0f;
            rs[tid] = 1.0f / fmaxf(c, 1.0f);
        }
        __syncthreads();
    }

    const int npass = HAS_A2 ? 2 : 1;
    for (int pass = 0; pass < npass; ++pass) {
        const float* __restrict__ A = (pass == 0) ? A1 : A2;
        const float* __restrict__ W = (pass == 0) ? W1 : W2;
        for (int k0 = 0; k0 < K; k0 += KC) {
            // stage A tile [64][32]
            #pragma unroll
            for (int i = 0; i < (TM * KC) / 256; ++i) {
                int e = tid + i * 256;
                int r = e >> 5, c = e & 31;
                int row = row0 + r;
                float v = (row < M) ? A[(size_t)row * K + k0 + c] : 0.0f;
                if (MEAN && pass == 0) v *= rs[r];
                As[r][c] = v;
            }
            // stage W tile [32][128]
            #pragma unroll
            for (int i = 0; i < (KC * N) / 256; ++i) {
                int e = tid + i * 256;
                Ws[e >> 7][e & 127] = W[(size_t)(k0 + (e >> 7)) * N + (e & 127)];
            }
            __syncthreads();
            #pragma unroll
            for (int kk = 0; kk < KC; ++kk) {
                float4 w = *(const float4*)&Ws[kk][c0];
                #pragma unroll
                for (int r = 0; r < 8; ++r) {
                    float a = As[r0 + r][kk];
                    acc[r][0] = fmaf(a, w.x, acc[r][0]);
                    acc[r][1] = fmaf(a, w.y, acc[r][1]);
                    acc[r][2] = fmaf(a, w.z, acc[r][2]);
                    acc[r][3] = fmaf(a, w.w, acc[r][3]);
                }
            }
            __syncthreads();
        }
    }

    float4 b = *(const float4*)&bias[c0];
    #pragma unroll
    for (int r = 0; r < 8; ++r) {
        int row = row0 + r0 + r;
        if (row < M) {
            float4 o;
            o.x = acc[r][0] + b.x;
            o.y = acc[r][1] + b.y;
            o.z = acc[r][2] + b.z;
            o.w = acc[r][3] + b.w;
            if (RELU) {
                o.x = fmaxf(o.x, 0.f); o.y = fmaxf(o.y, 0.f);
                o.z = fmaxf(o.z, 0.f); o.w = fmaxf(o.w, 0.f);
            }
            *(float4*)&C[(size_t)row * N + c0] = o;
        }
    }
}

// ---------------------------------------------------------------------------
// Scatter-add for segment mean: 32 lanes per edge, float4 per lane.
// ---------------------------------------------------------------------------
__global__ __launch_bounds__(256)
void scatter_kernel(const float* __restrict__ z,
                    const int* __restrict__ src, const int* __restrict__ dst,
                    float* __restrict__ agg, float* __restrict__ cnt, int nE)
{
    int t = blockIdx.x * 256 + threadIdx.x;
    int e = t >> 5;
    if (e >= nE) return;
    int lane = t & 31;
    int s = src[e], d = dst[e];
    float4 v = *(const float4*)&z[(size_t)s * H + lane * 4];
    float* p = &agg[(size_t)d * H + lane * 4];
    atomicAdd(p + 0, v.x);
    atomicAdd(p + 1, v.y);
    atomicAdd(p + 2, v.z);
    atomicAdd(p + 3, v.w);
    if (lane == 0) atomicAdd(&cnt[d], 1.0f);
}

// ---------------------------------------------------------------------------
// Edge decoder: per 32-edge tile, z = [hs[src] | hd[dst]] (256),
// y = relu(z@W1 + b1), out = sigmoid(y.W2 + b2).
// 256 threads; thread => 4 edges x 8 cols; W2-dot reduced over 32-lane groups.
// ---------------------------------------------------------------------------
__global__ __launch_bounds__(256)
void decoder_kernel(const float* __restrict__ hs, const float* __restrict__ hd,
                    const int* __restrict__ lsrc, const int* __restrict__ ldst,
                    const float* __restrict__ W1, const float* __restrict__ b1,
                    const float* __restrict__ W2, const float* __restrict__ b2,
                    float* __restrict__ out, int nE)
{
    constexpr int TE = 32, KC = 32;
    __shared__ float Zs[TE][256];
    __shared__ float Ws[KC][256];
    __shared__ int isrc[TE], idst[TE];

    const int tid = threadIdx.x;
    const int e0  = blockIdx.x * TE;

    if (tid < TE) {
        int e = min(e0 + tid, nE - 1);
        isrc[tid] = lsrc[e];
        idst[tid] = ldst[e];
    }
    __syncthreads();

    // gather 32 edges x 256 features into LDS (float4 granularity)
    #pragma unroll
    for (int i = 0; i < 8; ++i) {
        int q = tid + i * 256;          // float4 index, 2048 total
        int e = q >> 6, part = q & 63;  // 64 float4 per edge
        const float* p = (part < 32)
            ? (hs + (size_t)isrc[e] * H + part * 4)
            : (hd + (size_t)idst[e] * H + (part - 32) * 4);
        *(float4*)&Zs[e][part * 4] = *(const float4*)p;
    }
    __syncthreads();

    const int c0 = (tid & 31) * 8;
    const int r0 = (tid >> 5) * 4;
    float acc[4][8];
    #pragma unroll
    for (int r = 0; r < 4; ++r)
        #pragma unroll
        for (int c = 0; c < 8; ++c) acc[r][c] = 0.f;

    for (int k0 = 0; k0 < 256; k0 += KC) {
        #pragma unroll
        for (int i = 0; i < 8; ++i) {
            int q = tid + i * 256;          // float4 index, 2048 total
            int r = q >> 6, c = (q & 63) * 4;
            *(float4*)&Ws[r][c] = *(const float4*)&W1[(size_t)(k0 + r) * 256 + c];
        }
        __syncthreads();
        #pragma unroll
        for (int kk = 0; kk < KC; ++kk) {
            float4 wa = *(const float4*)&Ws[kk][c0];
            float4 wb = *(const float4*)&Ws[kk][c0 + 4];
            #pragma unroll
            for (int r = 0; r < 4; ++r) {
                float a = Zs[r0 + r][k0 + kk];
                acc[r][0] = fmaf(a, wa.x, acc[r][0]);
                acc[r][1] = fmaf(a, wa.y, acc[r][1]);
                acc[r][2] = fmaf(a, wa.z, acc[r][2]);
                acc[r][3] = fmaf(a, wa.w, acc[r][3]);
                acc[r][4] = fmaf(a, wb.x, acc[r][4]);
                acc[r][5] = fmaf(a, wb.y, acc[r][5]);
                acc[r][6] = fmaf(a, wb.z, acc[r][6]);
                acc[r][7] = fmaf(a, wb.w, acc[r][7]);
            }
        }
        __syncthreads();
    }

    float4 b1a = *(const float4*)&b1[c0];
    float4 b1b = *(const float4*)&b1[c0 + 4];
    float4 w2a = *(const float4*)&W2[c0];
    float4 w2b = *(const float4*)&W2[c0 + 4];
    float bb   = b2[0];

    #pragma unroll
    for (int r = 0; r < 4; ++r) {
        float p = 0.f;
        p += fmaxf(acc[r][0] + b1a.x, 0.f) * w2a.x;
        p += fmaxf(acc[r][1] + b1a.y, 0.f) * w2a.y;
        p += fmaxf(acc[r][2] + b1a.z, 0.f) * w2a.z;
        p += fmaxf(acc[r][3] + b1a.w, 0.f) * w2a.w;
        p += fmaxf(acc[r][4] + b1b.x, 0.f) * w2b.x;
        p += fmaxf(acc[r][5] + b1b.y, 0.f) * w2b.y;
        p += fmaxf(acc[r][6] + b1b.z, 0.f) * w2b.z;
        p += fmaxf(acc[r][7] + b1b.w, 0.f) * w2b.w;
        #pragma unroll
        for (int m = 16; m >= 1; m >>= 1)
            p += __shfl_xor(p, m);
        if ((tid & 31) == 0) {
            int e = e0 + r0 + r;
            if (e < nE) out[e] = 1.0f / (1.0f + expf(-(p + bb)));
        }
    }
}

// ---------------------------------------------------------------------------
extern "C" void kernel_launch(void* const* d_in, const int* in_sizes, int n_in,
                              void* d_out, int out_size, void* d_ws, size_t ws_size,
                              hipStream_t stream)
{
    const float* x_m      = (const float*)d_in[0];
    const float* x_e      = (const float*)d_in[1];
    const int*   src_m2e  = (const int*)d_in[2];
    const int*   dst_m2e  = (const int*)d_in[3];
    const int*   src_e2m  = (const int*)d_in[4];
    const int*   dst_e2m  = (const int*)d_in[5];
    const int*   lsrc_m2e = (const int*)d_in[6];
    const int*   ldst_m2e = (const int*)d_in[7];
    const int*   lsrc_e2m = (const int*)d_in[8];
    const int*   ldst_e2m = (const int*)d_in[9];
    const float* Wp_m   = (const float*)d_in[10];
    const float* bp_m   = (const float*)d_in[11];
    const float* Wp_e   = (const float*)d_in[12];
    const float* bp_e   = (const float*)d_in[13];
    const float* Wl_m2e = (const float*)d_in[14];
    const float* bl_m2e = (const float*)d_in[15];
    const float* Wr_m2e = (const float*)d_in[16];
    const float* Wl_e2m = (const float*)d_in[17];
    const float* bl_e2m = (const float*)d_in[18];
    const float* Wr_e2m = (const float*)d_in[19];
    const float* Wffw_m = (const float*)d_in[20];
    const float* bffw_m = (const float*)d_in[21];
    const float* Wffw_e = (const float*)d_in[22];
    const float* bffw_e = (const float*)d_in[23];
    const float* Wproj_m = (const float*)d_in[24];
    const float* bproj_m = (const float*)d_in[25];
    const float* Wproj_e = (const float*)d_in[26];
    const float* bproj_e = (const float*)d_in[27];
    const float* Wmlp_m2e = (const float*)d_in[28];
    const float* bmlp_m2e = (const float*)d_in[29];
    const float* Wout_m2e = (const float*)d_in[30];
    const float* bout_m2e = (const float*)d_in[31];
    const float* Wmlp_e2m = (const float*)d_in[32];
    const float* bmlp_e2m = (const float*)d_in[33];
    const float* Wout_e2m = (const float*)d_in[34];
    const float* bout_e2m = (const float*)d_in[35];

    float* out = (float*)d_out;
    float* ws  = (float*)d_ws;
    float* A_m   = ws;                          // z_m -> h_ffw_m
    float* A_e   = A_m + (size_t)N_M * H;       // z_e -> h_ffw_e
    float* B_m   = A_e + (size_t)N_E * H;       // agg_m -> h_m -> h_proj_m
    float* B_e   = B_m + (size_t)N_M * H;       // agg_e -> h_e -> h_proj_e
    float* cnt_m = B_e + (size_t)N_E * H;
    float* cnt_e = cnt_m + N_M;

    dim3 blk(256);
    dim3 gm((N_M + 63) / 64), ge((N_E + 63) / 64);

    // 1) per-type input projections
    gemm_kernel<FM, false, false, false><<<gm, blk, 0, stream>>>(
        x_m, nullptr, Wp_m, nullptr, nullptr, bp_m, A_m, N_M);
    gemm_kernel<FE, false, false, false><<<ge, blk, 0, stream>>>(
        x_e, nullptr, Wp_e, nullptr, nullptr, bp_e, A_e, N_E);

    // 2) zero agg buffers + counts (contiguous region)
    hipMemsetAsync(B_m, 0,
        sizeof(float) * ((size_t)N_M * H + (size_t)N_E * H + N_M + N_E), stream);

    // 3) scatter-add neighbor features + degree counts
    dim3 gs((NEDGE * 32 + 255) / 256);
    scatter_kernel<<<gs, blk, 0, stream>>>(A_e, src_e2m, dst_e2m, B_m, cnt_m, NEDGE);
    scatter_kernel<<<gs, blk, 0, stream>>>(A_m, src_m2e, dst_m2e, B_e, cnt_e, NEDGE);

    // 4) SAGE combine + relu (in place: B = relu(mean(B)@Wl + bl + A@Wr))
    gemm_kernel<H, true, true, true><<<gm, blk, 0, stream>>>(
        B_m, cnt_m, Wl_e2m, A_m, Wr_e2m, bl_e2m, B_m, N_M);
    gemm_kernel<H, true, true, true><<<ge, blk, 0, stream>>>(
        B_e, cnt_e, Wl_m2e, A_e, Wr_m2e, bl_m2e, B_e, N_E);

    // 5) ffw + relu: B -> A
    gemm_kernel<H, false, true, false><<<gm, blk, 0, stream>>>(
        B_m, nullptr, Wffw_m, nullptr, nullptr, bffw_m, A_m, N_M);
    gemm_kernel<H, false, true, false><<<ge, blk, 0, stream>>>(
        B_e, nullptr, Wffw_e, nullptr, nullptr, bffw_e, A_e, N_E);

    // 6) output projection: A -> B
    gemm_kernel<H, false, false, false><<<gm, blk, 0, stream>>>(
        A_m, nullptr, Wproj_m, nullptr, nullptr, bproj_m, B_m, N_M);
    gemm_kernel<H, false, false, false><<<ge, blk, 0, stream>>>(
        A_e, nullptr, Wproj_e, nullptr, nullptr, bproj_e, B_e, N_E);

    // 7) per-edge-type decoders
    dim3 gd((NLBL + 31) / 32);
    decoder_kernel<<<gd, blk, 0, stream>>>(
        B_m, B_e, lsrc_m2e, ldst_m2e, Wmlp_m2e, bmlp_m2e, Wout_m2e, bout_m2e,
        out, NLBL);
    decoder_kernel<<<gd, blk, 0, stream>>>(
        B_e, B_m, lsrc_e2m, ldst_e2m, Wmlp_e2m, bmlp_e2m, Wout_e2m, bout_e2m,
        out + NLBL, NLBL);
}

// Round 2
// 2534.597 us; speedup vs baseline: 2.2819x; 2.2819x over previous
//
#include <hip/hip_runtime.h>
#include <math.h>

#define N_M 100000
#define N_E 50000
#define FM 256
#define FE 64
#define H 128
#define NEDGE 1000000
#define NLBL 250000

// ---------------------------------------------------------------------------
// Generic tiled GEMM: C[M,128] = act( A1 @ W1 [+ A2 @ W2] + bias )
// TM=64 rows per block, 256 threads, each thread 8 rows x 4 cols.
// In-place safe when C == A1 (or A2): each output row-block depends only on
// the same input rows, and all k-chunks are consumed before the epilogue.
// ---------------------------------------------------------------------------
template<int K, bool HAS_A2, bool RELU>
__global__ __launch_bounds__(256)
void gemm_kernel(const float* __restrict__ A1,
                 const float* __restrict__ W1,
                 const float* __restrict__ A2,
                 const float* __restrict__ W2,
                 const float* __restrict__ bias,
                 float* __restrict__ C, int M)
{
    constexpr int TM = 64, KC = 32, N = 128;
    __shared__ float As[TM][KC + 1];
    __shared__ float Ws[KC][N];

    const int tid  = threadIdx.x;
    const int row0 = blockIdx.x * TM;
    const int c0   = (tid & 31) * 4;
    const int r0   = (tid >> 5) * 8;

    float acc[8][4];
    #pragma unroll
    for (int r = 0; r < 8; ++r) {
        acc[r][0] = 0.f; acc[r][1] = 0.f; acc[r][2] = 0.f; acc[r][3] = 0.f;
    }

    const int npass = HAS_A2 ? 2 : 1;
    for (int pass = 0; pass < npass; ++pass) {
        const float* __restrict__ A = (pass == 0) ? A1 : A2;
        const float* __restrict__ W = (pass == 0) ? W1 : W2;
        for (int k0 = 0; k0 < K; k0 += KC) {
            #pragma unroll
            for (int i = 0; i < (TM * KC) / 256; ++i) {
                int e = tid + i * 256;
                int r = e >> 5, c = e & 31;
                int row = row0 + r;
                As[r][c] = (row < M) ? A[(size_t)row * K + k0 + c] : 0.0f;
            }
            #pragma unroll
            for (int i = 0; i < (KC * N) / 256; ++i) {
                int e = tid + i * 256;
                Ws[e >> 7][e & 127] = W[(size_t)(k0 + (e >> 7)) * N + (e & 127)];
            }
            __syncthreads();
            #pragma unroll
            for (int kk = 0; kk < KC; ++kk) {
                float4 w = *(const float4*)&Ws[kk][c0];
                #pragma unroll
                for (int r = 0; r < 8; ++r) {
                    float a = As[r0 + r][kk];
                    acc[r][0] = fmaf(a, w.x, acc[r][0]);
                    acc[r][1] = fmaf(a, w.y, acc[r][1]);
                    acc[r][2] = fmaf(a, w.z, acc[r][2]);
                    acc[r][3] = fmaf(a, w.w, acc[r][3]);
                }
            }
            __syncthreads();
        }
    }

    float4 b = *(const float4*)&bias[c0];
    #pragma unroll
    for (int r = 0; r < 8; ++r) {
        int row = row0 + r0 + r;
        if (row < M) {
            float4 o;
            o.x = acc[r][0] + b.x;
            o.y = acc[r][1] + b.y;
            o.z = acc[r][2] + b.z;
            o.w = acc[r][3] + b.w;
            if (RELU) {
                o.x = fmaxf(o.x, 0.f); o.y = fmaxf(o.y, 0.f);
                o.z = fmaxf(o.z, 0.f); o.w = fmaxf(o.w, 0.f);
            }
            *(float4*)&C[(size_t)row * N + c0] = o;
        }
    }
}

// ---------------------------------------------------------------------------
// CSR construction: histogram -> 2-level exclusive scan -> cursor fill.
// ---------------------------------------------------------------------------
__global__ __launch_bounds__(256)
void hist_both_kernel(const int* __restrict__ dst_e2m,
                      const int* __restrict__ dst_m2e,
                      int* __restrict__ cnt_m, int* __restrict__ cnt_e)
{
    int t = blockIdx.x * 256 + threadIdx.x;
    if (t < NEDGE)          atomicAdd(&cnt_m[dst_e2m[t]], 1);
    else if (t < 2 * NEDGE) atomicAdd(&cnt_e[dst_m2e[t - NEDGE]], 1);
}

// per-block (4096 elems) exclusive scan + block totals
__global__ __launch_bounds__(256)
void scan_local_kernel(const int* __restrict__ in, int* __restrict__ out,
                       int* __restrict__ partials, int n)
{
    __shared__ int ts[256];
    const int tid = threadIdx.x;
    int i0 = blockIdx.x * 4096 + tid * 16;
    int vals[16];
    int tsum = 0;
    #pragma unroll
    for (int i = 0; i < 16; ++i) {
        int idx = i0 + i;
        int v = (idx < n) ? in[idx] : 0;
        vals[i] = tsum;        // exclusive within thread
        tsum += v;
    }
    ts[tid] = tsum;
    __syncthreads();
    for (int off = 1; off < 256; off <<= 1) {
        int v = (tid >= off) ? ts[tid - off] : 0;
        __syncthreads();
        ts[tid] += v;
        __syncthreads();
    }
    int texcl = ts[tid] - tsum;
    #pragma unroll
    for (int i = 0; i < 16; ++i) {
        int idx = i0 + i;
        if (idx < n) out[idx] = texcl + vals[i];
    }
    if (tid == 255) partials[blockIdx.x] = ts[255];
}

__global__ void scan_partials_kernel(int* partials, int np)
{
    if (threadIdx.x == 0) {
        int s = 0;
        for (int i = 0; i < np; ++i) { int v = partials[i]; partials[i] = s; s += v; }
    }
}

__global__ __launch_bounds__(256)
void scan_add_kernel(int* __restrict__ off, const int* __restrict__ partials,
                     int* __restrict__ cur, int n, int total)
{
    int idx = blockIdx.x * 256 + threadIdx.x;
    if (idx < n) {
        int v = off[idx] + partials[idx >> 12];
        off[idx] = v;
        cur[idx] = v;
    } else if (idx == n) {
        off[n] = total;
    }
}

__global__ __launch_bounds__(256)
void fill_both_kernel(const int* __restrict__ src_e2m, const int* __restrict__ dst_e2m,
                      const int* __restrict__ src_m2e, const int* __restrict__ dst_m2e,
                      int* __restrict__ cur_m, int* __restrict__ cur_e,
                      int* __restrict__ csr_m, int* __restrict__ csr_e)
{
    int t = blockIdx.x * 256 + threadIdx.x;
    if (t < NEDGE) {
        int p = atomicAdd(&cur_m[dst_e2m[t]], 1);
        csr_m[p] = src_e2m[t];
    } else if (t < 2 * NEDGE) {
        int e = t - NEDGE;
        int p = atomicAdd(&cur_e[dst_m2e[e]], 1);
        csr_e[p] = src_m2e[e];
    }
}

// ---------------------------------------------------------------------------
// Gather-based segment mean: one 32-lane group per destination node.
// Each lane owns 4 contiguous floats (float4); neighbor rows are 512B
// contiguous reads that mostly hit L2/L3. No atomics.
// ---------------------------------------------------------------------------
__global__ __launch_bounds__(256)
void gather_mean_kernel(const float* __restrict__ z,
                        const int* __restrict__ csr, const int* __restrict__ off,
                        float* __restrict__ outm, int n)
{
    int g = (blockIdx.x * 256 + threadIdx.x) >> 5;
    if (g >= n) return;
    int lane = threadIdx.x & 31;
    int a = off[g], b = off[g + 1];
    float4 s = {0.f, 0.f, 0.f, 0.f};
    for (int e = a; e < b; ++e) {
        int sidx = csr[e];
        float4 v = *(const float4*)&z[(size_t)sidx * H + lane * 4];
        s.x += v.x; s.y += v.y; s.z += v.z; s.w += v.w;
    }
    float inv = 1.0f / fmaxf((float)(b - a), 1.0f);
    s.x *= inv; s.y *= inv; s.z *= inv; s.w *= inv;
    *(float4*)&outm[(size_t)g * H + lane * 4] = s;
}

// ---------------------------------------------------------------------------
// Edge decoder: per 32-edge tile, z = [hs[src] | hd[dst]] (256),
// y = relu(z@W1 + b1), out = sigmoid(y.W2 + b2).
// ---------------------------------------------------------------------------
__global__ __launch_bounds__(256)
void decoder_kernel(const float* __restrict__ hs, const float* __restrict__ hd,
                    const int* __restrict__ lsrc, const int* __restrict__ ldst,
                    const float* __restrict__ W1, const float* __restrict__ b1,
                    const float* __restrict__ W2, const float* __restrict__ b2,
                    float* __restrict__ out, int nE)
{
    constexpr int TE = 32, KC = 32;
    __shared__ float Zs[TE][256];
    __shared__ float Ws[KC][256];
    __shared__ int isrc[TE], idst[TE];

    const int tid = threadIdx.x;
    const int e0  = blockIdx.x * TE;

    if (tid < TE) {
        int e = min(e0 + tid, nE - 1);
        isrc[tid] = lsrc[e];
        idst[tid] = ldst[e];
    }
    __syncthreads();

    #pragma unroll
    for (int i = 0; i < 8; ++i) {
        int q = tid + i * 256;          // float4 index, 2048 total
        int e = q >> 6, part = q & 63;  // 64 float4 per edge
        const float* p = (part < 32)
            ? (hs + (size_t)isrc[e] * H + part * 4)
            : (hd + (size_t)idst[e] * H + (part - 32) * 4);
        *(float4*)&Zs[e][part * 4] = *(const float4*)p;
    }
    __syncthreads();

    const int c0 = (tid & 31) * 8;
    const int r0 = (tid >> 5) * 4;
    float acc[4][8];
    #pragma unroll
    for (int r = 0; r < 4; ++r)
        #pragma unroll
        for (int c = 0; c < 8; ++c) acc[r][c] = 0.f;

    for (int k0 = 0; k0 < 256; k0 += KC) {
        #pragma unroll
        for (int i = 0; i < 8; ++i) {
            int q = tid + i * 256;
            int r = q >> 6, c = (q & 63) * 4;
            *(float4*)&Ws[r][c] = *(const float4*)&W1[(size_t)(k0 + r) * 256 + c];
        }
        __syncthreads();
        #pragma unroll
        for (int kk = 0; kk < KC; ++kk) {
            float4 wa = *(const float4*)&Ws[kk][c0];
            float4 wb = *(const float4*)&Ws[kk][c0 + 4];
            #pragma unroll
            for (int r = 0; r < 4; ++r) {
                float a = Zs[r0 + r][k0 + kk];
                acc[r][0] = fmaf(a, wa.x, acc[r][0]);
                acc[r][1] = fmaf(a, wa.y, acc[r][1]);
                acc[r][2] = fmaf(a, wa.z, acc[r][2]);
                acc[r][3] = fmaf(a, wa.w, acc[r][3]);
                acc[r][4] = fmaf(a, wb.x, acc[r][4]);
                acc[r][5] = fmaf(a, wb.y, acc[r][5]);
                acc[r][6] = fmaf(a, wb.z, acc[r][6]);
                acc[r][7] = fmaf(a, wb.w, acc[r][7]);
            }
        }
        __syncthreads();
    }

    float4 b1a = *(const float4*)&b1[c0];
    float4 b1b = *(const float4*)&b1[c0 + 4];
    float4 w2a = *(const float4*)&W2[c0];
    float4 w2b = *(const float4*)&W2[c0 + 4];
    float bb   = b2[0];

    #pragma unroll
    for (int r = 0; r < 4; ++r) {
        float p = 0.f;
        p += fmaxf(acc[r][0] + b1a.x, 0.f) * w2a.x;
        p += fmaxf(acc[r][1] + b1a.y, 0.f) * w2a.y;
        p += fmaxf(acc[r][2] + b1a.z, 0.f) * w2a.z;
        p += fmaxf(acc[r][3] + b1a.w, 0.f) * w2a.w;
        p += fmaxf(acc[r][4] + b1b.x, 0.f) * w2b.x;
        p += fmaxf(acc[r][5] + b1b.y, 0.f) * w2b.y;
        p += fmaxf(acc[r][6] + b1b.z, 0.f) * w2b.z;
        p += fmaxf(acc[r][7] + b1b.w, 0.f) * w2b.w;
        #pragma unroll
        for (int m = 16; m >= 1; m >>= 1)
            p += __shfl_xor(p, m);
        if ((tid & 31) == 0) {
            int e = e0 + r0 + r;
            if (e < nE) out[e] = 1.0f / (1.0f + expf(-(p + bb)));
        }
    }
}

// ---------------------------------------------------------------------------
extern "C" void kernel_launch(void* const* d_in, const int* in_sizes, int n_in,
                              void* d_out, int out_size, void* d_ws, size_t ws_size,
                              hipStream_t stream)
{
    const float* x_m      = (const float*)d_in[0];
    const float* x_e      = (const float*)d_in[1];
    const int*   src_m2e  = (const int*)d_in[2];
    const int*   dst_m2e  = (const int*)d_in[3];
    const int*   src_e2m  = (const int*)d_in[4];
    const int*   dst_e2m  = (const int*)d_in[5];
    const int*   lsrc_m2e = (const int*)d_in[6];
    const int*   ldst_m2e = (const int*)d_in[7];
    const int*   lsrc_e2m = (const int*)d_in[8];
    const int*   ldst_e2m = (const int*)d_in[9];
    const float* Wp_m   = (const float*)d_in[10];
    const float* bp_m   = (const float*)d_in[11];
    const float* Wp_e   = (const float*)d_in[12];
    const float* bp_e   = (const float*)d_in[13];
    const float* Wl_m2e = (const float*)d_in[14];
    const float* bl_m2e = (const float*)d_in[15];
    const float* Wr_m2e = (const float*)d_in[16];
    const float* Wl_e2m = (const float*)d_in[17];
    const float* bl_e2m = (const float*)d_in[18];
    const float* Wr_e2m = (const float*)d_in[19];
    const float* Wffw_m = (const float*)d_in[20];
    const float* bffw_m = (const float*)d_in[21];
    const float* Wffw_e = (const float*)d_in[22];
    const float* bffw_e = (const float*)d_in[23];
    const float* Wproj_m = (const float*)d_in[24];
    const float* bproj_m = (const float*)d_in[25];
    const float* Wproj_e = (const float*)d_in[26];
    const float* bproj_e = (const float*)d_in[27];
    const float* Wmlp_m2e = (const float*)d_in[28];
    const float* bmlp_m2e = (const float*)d_in[29];
    const float* Wout_m2e = (const float*)d_in[30];
    const float* bout_m2e = (const float*)d_in[31];
    const float* Wmlp_e2m = (const float*)d_in[32];
    const float* bmlp_e2m = (const float*)d_in[33];
    const float* Wout_e2m = (const float*)d_in[34];
    const float* bout_e2m = (const float*)d_in[35];

    float* out = (float*)d_out;
    float* ws  = (float*)d_ws;
    // float region
    float* A_m = ws;                        // z_m -> h_ffw_m
    float* A_e = A_m + (size_t)N_M * H;     // z_e -> h_ffw_e
    float* B_m = A_e + (size_t)N_E * H;     // mean_m -> h_m -> h_proj_m
    float* B_e = B_m + (size_t)N_M * H;     // mean_e -> h_e -> h_proj_e
    // int region
    int* ip    = (int*)(B_e + (size_t)N_E * H);
    int* cnt_m = ip;                 ip += N_M;
    int* cnt_e = ip;                 ip += N_E;      // cnt_m/cnt_e contiguous (one memset)
    int* off_m = ip;                 ip += N_M + 1;
    int* off_e = ip;                 ip += N_E + 1;
    int* cur_m = ip;                 ip += N_M;
    int* cur_e = ip;                 ip += N_E;
    int* par_m = ip;                 ip += 32;
    int* par_e = ip;                 ip += 32;
    int* csr_m = ip;                 ip += NEDGE;    // srcs (elements) grouped by dst material
    int* csr_e = ip;                 ip += NEDGE;    // srcs (materials) grouped by dst element

    dim3 blk(256);
    dim3 gm((N_M + 63) / 64), ge((N_E + 63) / 64);

    // 1) per-type input projections
    gemm_kernel<FM, false, false><<<gm, blk, 0, stream>>>(
        x_m, Wp_m, nullptr, nullptr, bp_m, A_m, N_M);
    gemm_kernel<FE, false, false><<<ge, blk, 0, stream>>>(
        x_e, Wp_e, nullptr, nullptr, bp_e, A_e, N_E);

    // 2) CSR build (counting sort of edges by destination)
    hipMemsetAsync(cnt_m, 0, sizeof(int) * (N_M + N_E), stream);
    dim3 g2e((2 * NEDGE + 255) / 256);
    hist_both_kernel<<<g2e, blk, 0, stream>>>(dst_e2m, dst_m2e, cnt_m, cnt_e);

    const int nb_m = (N_M + 4095) / 4096;   // 25
    const int nb_e = (N_E + 4095) / 4096;   // 13
    scan_local_kernel<<<dim3(nb_m), blk, 0, stream>>>(cnt_m, off_m, par_m, N_M);
    scan_local_kernel<<<dim3(nb_e), blk, 0, stream>>>(cnt_e, off_e, par_e, N_E);
    scan_partials_kernel<<<dim3(1), dim3(64), 0, stream>>>(par_m, nb_m);
    scan_partials_kernel<<<dim3(1), dim3(64), 0, stream>>>(par_e, nb_e);
    scan_add_kernel<<<dim3((N_M + 256) / 256 + 1), blk, 0, stream>>>(off_m, par_m, cur_m, N_M, NEDGE);
    scan_add_kernel<<<dim3((N_E + 256) / 256 + 1), blk, 0, stream>>>(off_e, par_e, cur_e, N_E, NEDGE);

    fill_both_kernel<<<g2e, blk, 0, stream>>>(src_e2m, dst_e2m, src_m2e, dst_m2e,
                                              cur_m, cur_e, csr_m, csr_e);

    // 3) gather-based segment mean (no feature atomics)
    gather_mean_kernel<<<dim3((N_M * 32 + 255) / 256), blk, 0, stream>>>(
        A_e, csr_m, off_m, B_m, N_M);
    gather_mean_kernel<<<dim3((N_E * 32 + 255) / 256), blk, 0, stream>>>(
        A_m, csr_e, off_e, B_e, N_E);

    // 4) SAGE combine + relu (in place: B = relu(B@Wl + A@Wr + bl))
    gemm_kernel<H, true, true><<<gm, blk, 0, stream>>>(
        B_m, Wl_e2m, A_m, Wr_e2m, bl_e2m, B_m, N_M);
    gemm_kernel<H, true, true><<<ge, blk, 0, stream>>>(
        B_e, Wl_m2e, A_e, Wr_m2e, bl_m2e, B_e, N_E);

    // 5) ffw + relu: B -> A
    gemm_kernel<H, false, true><<<gm, blk, 0, stream>>>(
        B_m, Wffw_m, nullptr, nullptr, bffw_m, A_m, N_M);
    gemm_kernel<H, false, true><<<ge, blk, 0, stream>>>(
        B_e, Wffw_e, nullptr, nullptr, bffw_e, A_e, N_E);

    // 6) output projection: A -> B
    gemm_kernel<H, false, false><<<gm, blk, 0, stream>>>(
        A_m, Wproj_m, nullptr, nullptr, bproj_m, B_m, N_M);
    gemm_kernel<H, false, false><<<ge, blk, 0, stream>>>(
        A_e, Wproj_e, nullptr, nullptr, bproj_e, B_e, N_E);

    // 7) per-edge-type decoders
    dim3 gd((NLBL + 31) / 32);
    decoder_kernel<<<gd, blk, 0, stream>>>(
        B_m, B_e, lsrc_m2e, ldst_m2e, Wmlp_m2e, bmlp_m2e, Wout_m2e, bout_m2e,
        out, NLBL);
    decoder_kernel<<<gd, blk, 0, stream>>>(
        B_e, B_m, lsrc_e2m, ldst_e2m, Wmlp_e2m, bmlp_e2m, Wout_e2m, bout_e2m,
        out + NLBL, NLBL);
}

// Round 3
// 694.521 us; speedup vs baseline: 8.3275x; 3.6494x over previous
//
#include <hip/hip_runtime.h>
#include <math.h>

#define N_M 100000
#define N_E 50000
#define FM 256
#define FE 64
#define H 128
#define NEDGE 1000000
#define NLBL 250000

typedef unsigned short u16;
typedef short bf16x8 __attribute__((ext_vector_type(8)));
typedef float f32x4  __attribute__((ext_vector_type(4)));
typedef u16 u16x8    __attribute__((ext_vector_type(8)));
typedef u16 u16x4    __attribute__((ext_vector_type(4)));

__device__ __forceinline__ u16 f2bf(float x) {
    unsigned u = __float_as_uint(x);
    u += 0x7FFF + ((u >> 16) & 1);           // RNE
    return (u16)(u >> 16);
}
__device__ __forceinline__ float bf2f(u16 h) {
    return __uint_as_float(((unsigned)h) << 16);
}

// ---------------------------------------------------------------------------
// Weight packing into mfma_f32_16x16x32_bf16 B-fragment order.
// For tile (kt,nt): lane l, j  ->  W[kt*32 + (l>>4)*8 + j][nt*16 + (l&15)]
// Packed at: ((tile)*64 + l)*8 + j   (16B contiguous per lane)
// ---------------------------------------------------------------------------
#define NPACK 14
struct PackDesc { const float* src; u16* dst; int K, N; };
struct PackArgs { PackDesc d[NPACK]; };

__global__ __launch_bounds__(64)
void pack_kernel(PackArgs args)
{
    PackDesc pd = args.d[blockIdx.y];
    int KT = pd.K / 32, NT = pd.N / 16;
    int tile = blockIdx.x;
    if (tile >= KT * NT) return;
    int kt = tile / NT, nt = tile % NT;
    int l = threadIdx.x;
    u16* dst = pd.dst + ((size_t)tile * 64 + l) * 8;
    #pragma unroll
    for (int j = 0; j < 8; ++j) {
        float v = pd.src[(size_t)(kt * 32 + (l >> 4) * 8 + j) * pd.N + nt * 16 + (l & 15)];
        dst[j] = f2bf(v);
    }
}

// ---------------------------------------------------------------------------
// MFMA GEMM: C[M,N](bf16) = act( A1@W1 [+ A2@W2] [+ bias] )
// Block = 256 thr = 4 waves; each wave: 16 rows x N cols. No LDS.
// A row-major (bf16 or fp32). W pre-packed. M % 16 == 0.
// ---------------------------------------------------------------------------
template<int K, int N, bool HAS_A2, bool RELU, bool A_FP32, bool HAS_BIAS>
__global__ __launch_bounds__(256)
void mfma_gemm(const void* __restrict__ A1, const void* __restrict__ A2,
               const u16* __restrict__ W1p, const u16* __restrict__ W2p,
               const float* __restrict__ bias, u16* __restrict__ C, int M)
{
    constexpr int NT = N / 16, KT = K / 32;
    const int wid = threadIdx.x >> 6, lane = threadIdx.x & 63;
    const int row0 = blockIdx.x * 64 + wid * 16;
    if (row0 >= M) return;
    const int l15 = lane & 15, l4 = lane >> 4;

    f32x4 acc[NT];
    #pragma unroll
    for (int nt = 0; nt < NT; ++nt) acc[nt] = (f32x4){0.f, 0.f, 0.f, 0.f};

    const int npass = HAS_A2 ? 2 : 1;
    for (int pass = 0; pass < npass; ++pass) {
        const void* A = pass ? A2 : A1;
        const u16* Wp = pass ? W2p : W1p;
        #pragma unroll
        for (int kt = 0; kt < KT; ++kt) {
            bf16x8 a;
            if constexpr (A_FP32) {
                const float* ap = (const float*)A + (size_t)(row0 + l15) * K + kt * 32 + l4 * 8;
                float4 f0 = *(const float4*)ap;
                float4 f1 = *(const float4*)(ap + 4);
                a[0] = (short)f2bf(f0.x); a[1] = (short)f2bf(f0.y);
                a[2] = (short)f2bf(f0.z); a[3] = (short)f2bf(f0.w);
                a[4] = (short)f2bf(f1.x); a[5] = (short)f2bf(f1.y);
                a[6] = (short)f2bf(f1.z); a[7] = (short)f2bf(f1.w);
            } else {
                a = *(const bf16x8*)((const u16*)A + (size_t)(row0 + l15) * K + kt * 32 + l4 * 8);
            }
            #pragma unroll
            for (int nt = 0; nt < NT; ++nt) {
                bf16x8 b = *(const bf16x8*)(Wp + ((size_t)(kt * NT + nt) * 64 + lane) * 8);
                acc[nt] = __builtin_amdgcn_mfma_f32_16x16x32_bf16(a, b, acc[nt], 0, 0, 0);
            }
        }
    }

    #pragma unroll
    for (int nt = 0; nt < NT; ++nt) {
        #pragma unroll
        for (int r = 0; r < 4; ++r) {
            int row = row0 + l4 * 4 + r;
            int col = nt * 16 + l15;
            float v = acc[nt][r];
            if (HAS_BIAS) v += bias[col];
            if (RELU) v = fmaxf(v, 0.f);
            C[(size_t)row * N + col] = f2bf(v);
        }
    }
}

// ---------------------------------------------------------------------------
// CSR construction (unchanged from round 2)
// ---------------------------------------------------------------------------
__global__ __launch_bounds__(256)
void hist_both_kernel(const int* __restrict__ dst_e2m,
                      const int* __restrict__ dst_m2e,
                      int* __restrict__ cnt_m, int* __restrict__ cnt_e)
{
    int t = blockIdx.x * 256 + threadIdx.x;
    if (t < NEDGE)          atomicAdd(&cnt_m[dst_e2m[t]], 1);
    else if (t < 2 * NEDGE) atomicAdd(&cnt_e[dst_m2e[t - NEDGE]], 1);
}

__global__ __launch_bounds__(256)
void scan_local_kernel(const int* __restrict__ in, int* __restrict__ out,
                       int* __restrict__ partials, int n)
{
    __shared__ int ts[256];
    const int tid = threadIdx.x;
    int i0 = blockIdx.x * 4096 + tid * 16;
    int vals[16];
    int tsum = 0;
    #pragma unroll
    for (int i = 0; i < 16; ++i) {
        int idx = i0 + i;
        int v = (idx < n) ? in[idx] : 0;
        vals[i] = tsum;
        tsum += v;
    }
    ts[tid] = tsum;
    __syncthreads();
    for (int off = 1; off < 256; off <<= 1) {
        int v = (tid >= off) ? ts[tid - off] : 0;
        __syncthreads();
        ts[tid] += v;
        __syncthreads();
    }
    int texcl = ts[tid] - tsum;
    #pragma unroll
    for (int i = 0; i < 16; ++i) {
        int idx = i0 + i;
        if (idx < n) out[idx] = texcl + vals[i];
    }
    if (tid == 255) partials[blockIdx.x] = ts[255];
}

__global__ void scan_partials_kernel(int* partials, int np)
{
    if (threadIdx.x == 0) {
        int s = 0;
        for (int i = 0; i < np; ++i) { int v = partials[i]; partials[i] = s; s += v; }
    }
}

__global__ __launch_bounds__(256)
void scan_add_kernel(int* __restrict__ off, const int* __restrict__ partials,
                     int* __restrict__ cur, int n, int total)
{
    int idx = blockIdx.x * 256 + threadIdx.x;
    if (idx < n) {
        int v = off[idx] + partials[idx >> 12];
        off[idx] = v;
        cur[idx] = v;
    } else if (idx == n) {
        off[n] = total;
    }
}

__global__ __launch_bounds__(256)
void fill_both_kernel(const int* __restrict__ src_e2m, const int* __restrict__ dst_e2m,
                      const int* __restrict__ src_m2e, const int* __restrict__ dst_m2e,
                      int* __restrict__ cur_m, int* __restrict__ cur_e,
                      int* __restrict__ csr_m, int* __restrict__ csr_e)
{
    int t = blockIdx.x * 256 + threadIdx.x;
    if (t < NEDGE) {
        int p = atomicAdd(&cur_m[dst_e2m[t]], 1);
        csr_m[p] = src_e2m[t];
    } else if (t < 2 * NEDGE) {
        int e = t - NEDGE;
        int p = atomicAdd(&cur_e[dst_m2e[e]], 1);
        csr_e[p] = src_m2e[e];
    }
}

// ---------------------------------------------------------------------------
// Gather-based segment mean on bf16: 32 lanes per dst node, 4 ch/lane.
// ---------------------------------------------------------------------------
__global__ __launch_bounds__(256)
void gather_mean_kernel(const u16* __restrict__ z,
                        const int* __restrict__ csr, const int* __restrict__ off,
                        u16* __restrict__ outm, int n)
{
    int g = (blockIdx.x * 256 + threadIdx.x) >> 5;
    if (g >= n) return;
    int lane = threadIdx.x & 31;
    int a = off[g], b = off[g + 1];
    float s0 = 0.f, s1 = 0.f, s2 = 0.f, s3 = 0.f;
    for (int e = a; e < b; ++e) {
        const u16x4 v = *(const u16x4*)&z[(size_t)csr[e] * H + lane * 4];
        s0 += bf2f(v[0]); s1 += bf2f(v[1]); s2 += bf2f(v[2]); s3 += bf2f(v[3]);
    }
    float inv = 1.0f / fmaxf((float)(b - a), 1.0f);
    u16x4 o;
    o[0] = f2bf(s0 * inv); o[1] = f2bf(s1 * inv);
    o[2] = f2bf(s2 * inv); o[3] = f2bf(s3 * inv);
    *(u16x4*)&outm[(size_t)g * H + lane * 4] = o;
}

// ---------------------------------------------------------------------------
// Edge decode: out[e] = sigmoid( relu(Us[s] + Ud[d] + b1) . W2 + b2 )
// 16 lanes per edge (16 ch each); each quarter-wave handles EPQ edges.
// ---------------------------------------------------------------------------
#define EPQ 8
#define NQ  31250   // ceil(NLBL / EPQ)

__global__ __launch_bounds__(256)
void edge_decode_kernel(const u16* __restrict__ Us, const u16* __restrict__ Ud,
                        const int* __restrict__ lsrc, const int* __restrict__ ldst,
                        const float* __restrict__ b1, const float* __restrict__ W2,
                        const float* __restrict__ b2, float* __restrict__ out)
{
    const int t  = blockIdx.x * 256 + threadIdx.x;
    const int q  = t >> 4;
    const int li = t & 15;
    if (q >= NQ) return;

    float w2v[16], b1v[16];
    #pragma unroll
    for (int j = 0; j < 4; ++j) {
        float4 w = *(const float4*)&W2[li * 16 + j * 4];
        float4 bb = *(const float4*)&b1[li * 16 + j * 4];
        w2v[j*4+0] = w.x; w2v[j*4+1] = w.y; w2v[j*4+2] = w.z; w2v[j*4+3] = w.w;
        b1v[j*4+0] = bb.x; b1v[j*4+1] = bb.y; b1v[j*4+2] = bb.z; b1v[j*4+3] = bb.w;
    }
    const float bout = b2[0];

    #pragma unroll
    for (int i = 0; i < EPQ; ++i) {
        int e = q + i * NQ;
        if (e >= NLBL) break;
        int s = lsrc[e], d = ldst[e];
        const u16* us = Us + (size_t)s * 256 + li * 16;
        const u16* ud = Ud + (size_t)d * 256 + li * 16;
        u16x8 sa = *(const u16x8*)us;
        u16x8 sb = *(const u16x8*)(us + 8);
        u16x8 da = *(const u16x8*)ud;
        u16x8 db = *(const u16x8*)(ud + 8);
        float acc = 0.f;
        #pragma unroll
        for (int j = 0; j < 8; ++j)
            acc += fmaxf(bf2f(sa[j]) + bf2f(da[j]) + b1v[j], 0.f) * w2v[j];
        #pragma unroll
        for (int j = 0; j < 8; ++j)
            acc += fmaxf(bf2f(sb[j]) + bf2f(db[j]) + b1v[8 + j], 0.f) * w2v[8 + j];
        acc += __shfl_xor(acc, 1, 16);
        acc += __shfl_xor(acc, 2, 16);
        acc += __shfl_xor(acc, 4, 16);
        acc += __shfl_xor(acc, 8, 16);
        if (li == 0) out[e] = 1.0f / (1.0f + expf(-(acc + bout)));
    }
}

// ---------------------------------------------------------------------------
extern "C" void kernel_launch(void* const* d_in, const int* in_sizes, int n_in,
                              void* d_out, int out_size, void* d_ws, size_t ws_size,
                              hipStream_t stream)
{
    const float* x_m      = (const float*)d_in[0];
    const float* x_e      = (const float*)d_in[1];
    const int*   src_m2e  = (const int*)d_in[2];
    const int*   dst_m2e  = (const int*)d_in[3];
    const int*   src_e2m  = (const int*)d_in[4];
    const int*   dst_e2m  = (const int*)d_in[5];
    const int*   lsrc_m2e = (const int*)d_in[6];
    const int*   ldst_m2e = (const int*)d_in[7];
    const int*   lsrc_e2m = (const int*)d_in[8];
    const int*   ldst_e2m = (const int*)d_in[9];
    const float* Wp_m   = (const float*)d_in[10];
    const float* bp_m   = (const float*)d_in[11];
    const float* Wp_e   = (const float*)d_in[12];
    const float* bp_e   = (const float*)d_in[13];
    const float* Wl_m2e = (const float*)d_in[14];
    const float* bl_m2e = (const float*)d_in[15];
    const float* Wr_m2e = (const float*)d_in[16];
    const float* Wl_e2m = (const float*)d_in[17];
    const float* bl_e2m = (const float*)d_in[18];
    const float* Wr_e2m = (const float*)d_in[19];
    const float* Wffw_m = (const float*)d_in[20];
    const float* bffw_m = (const float*)d_in[21];
    const float* Wffw_e = (const float*)d_in[22];
    const float* bffw_e = (const float*)d_in[23];
    const float* Wproj_m = (const float*)d_in[24];
    const float* bproj_m = (const float*)d_in[25];
    const float* Wproj_e = (const float*)d_in[26];
    const float* bproj_e = (const float*)d_in[27];
    const float* Wmlp_m2e = (const float*)d_in[28];
    const float* bmlp_m2e = (const float*)d_in[29];
    const float* Wout_m2e = (const float*)d_in[30];
    const float* bout_m2e = (const float*)d_in[31];
    const float* Wmlp_e2m = (const float*)d_in[32];
    const float* bmlp_e2m = (const float*)d_in[33];
    const float* Wout_e2m = (const float*)d_in[34];
    const float* bout_e2m = (const float*)d_in[35];

    float* out = (float*)d_out;

    // ---- workspace layout (bf16 elems unless noted) ----
    u16* B_m = (u16*)d_ws;                       // 12.8M  mean_m -> h_m
    u16* B_e = B_m + (size_t)N_M * H;            // 6.4M   mean_e -> h_e
    u16* U0  = B_e + (size_t)N_E * H;            // 51.2M region
    u16* A_m = U0;                               // z_m -> h_ffw_m (dead after proj)
    u16* A_e = A_m + (size_t)N_M * H;
    u16* Us  = U0;                               // 25.6M
    u16* Ud  = U0 + (size_t)N_M * 256;           // 25.6M
    int* ip    = (int*)(U0 + 2 * (size_t)N_M * 256);
    int* cnt_m = ip;                 ip += N_M;
    int* cnt_e = ip;                 ip += N_E;
    int* off_m = ip;                 ip += N_M + 1;
    int* off_e = ip;                 ip += N_E + 1;
    int* cur_m = ip;                 ip += N_M;
    int* cur_e = ip;                 ip += N_E;
    int* par_m = ip;                 ip += 32;
    int* par_e = ip;                 ip += 32;
    int* csr_m = ip;                 ip += NEDGE;
    int* csr_e = ip;                 ip += NEDGE;
    u16* pk = (u16*)(((uintptr_t)ip + 15) & ~(uintptr_t)15);
    u16* pWp_m   = pk;  pk += 256 * 128;
    u16* pWp_e   = pk;  pk += 64 * 128;
    u16* pWl_e2m = pk;  pk += 128 * 128;
    u16* pWr_e2m = pk;  pk += 128 * 128;
    u16* pWl_m2e = pk;  pk += 128 * 128;
    u16* pWr_m2e = pk;  pk += 128 * 128;
    u16* pWffw_m = pk;  pk += 128 * 128;
    u16* pWffw_e = pk;  pk += 128 * 128;
    u16* pWproj_m= pk;  pk += 128 * 128;
    u16* pWproj_e= pk;  pk += 128 * 128;
    u16* pW1a_m2e= pk;  pk += 128 * 256;
    u16* pW1b_m2e= pk;  pk += 128 * 256;
    u16* pW1a_e2m= pk;  pk += 128 * 256;
    u16* pW1b_e2m= pk;  pk += 128 * 256;

    dim3 blk(256);
    dim3 gm((N_M + 63) / 64), ge((N_E + 63) / 64);

    // 0) pack all weights into MFMA B-frag layout
    PackArgs pa;
    pa.d[0]  = { Wp_m,               pWp_m,    FM, H };
    pa.d[1]  = { Wp_e,               pWp_e,    FE, H };
    pa.d[2]  = { Wl_e2m,             pWl_e2m,  H,  H };
    pa.d[3]  = { Wr_e2m,             pWr_e2m,  H,  H };
    pa.d[4]  = { Wl_m2e,             pWl_m2e,  H,  H };
    pa.d[5]  = { Wr_m2e,             pWr_m2e,  H,  H };
    pa.d[6]  = { Wffw_m,             pWffw_m,  H,  H };
    pa.d[7]  = { Wffw_e,             pWffw_e,  H,  H };
    pa.d[8]  = { Wproj_m,            pWproj_m, H,  H };
    pa.d[9]  = { Wproj_e,            pWproj_e, H,  H };
    pa.d[10] = { Wmlp_m2e,           pW1a_m2e, H,  256 };
    pa.d[11] = { Wmlp_m2e + 128*256, pW1b_m2e, H,  256 };
    pa.d[12] = { Wmlp_e2m,           pW1a_e2m, H,  256 };
    pa.d[13] = { Wmlp_e2m + 128*256, pW1b_e2m, H,  256 };
    pack_kernel<<<dim3(64, NPACK), dim3(64), 0, stream>>>(pa);

    // 1) input projections (fp32 A -> bf16 out)
    mfma_gemm<FM, H, false, false, true, true><<<gm, blk, 0, stream>>>(
        x_m, nullptr, pWp_m, nullptr, bp_m, A_m, N_M);
    mfma_gemm<FE, H, false, false, true, true><<<ge, blk, 0, stream>>>(
        x_e, nullptr, pWp_e, nullptr, bp_e, A_e, N_E);

    // 2) CSR build
    hipMemsetAsync(cnt_m, 0, sizeof(int) * (N_M + N_E), stream);
    dim3 g2e((2 * NEDGE + 255) / 256);
    hist_both_kernel<<<g2e, blk, 0, stream>>>(dst_e2m, dst_m2e, cnt_m, cnt_e);
    const int nb_m = (N_M + 4095) / 4096;
    const int nb_e = (N_E + 4095) / 4096;
    scan_local_kernel<<<dim3(nb_m), blk, 0, stream>>>(cnt_m, off_m, par_m, N_M);
    scan_local_kernel<<<dim3(nb_e), blk, 0, stream>>>(cnt_e, off_e, par_e, N_E);
    scan_partials_kernel<<<dim3(1), dim3(64), 0, stream>>>(par_m, nb_m);
    scan_partials_kernel<<<dim3(1), dim3(64), 0, stream>>>(par_e, nb_e);
    scan_add_kernel<<<dim3((N_M + 256) / 256 + 1), blk, 0, stream>>>(off_m, par_m, cur_m, N_M, NEDGE);
    scan_add_kernel<<<dim3((N_E + 256) / 256 + 1), blk, 0, stream>>>(off_e, par_e, cur_e, N_E, NEDGE);
    fill_both_kernel<<<g2e, blk, 0, stream>>>(src_e2m, dst_e2m, src_m2e, dst_m2e,
                                              cur_m, cur_e, csr_m, csr_e);

    // 3) gather segment mean (bf16)
    gather_mean_kernel<<<dim3((N_M * 32 + 255) / 256), blk, 0, stream>>>(
        A_e, csr_m, off_m, B_m, N_M);
    gather_mean_kernel<<<dim3((N_E * 32 + 255) / 256), blk, 0, stream>>>(
        A_m, csr_e, off_e, B_e, N_E);

    // 4) SAGE combine + relu (in place on B)
    mfma_gemm<H, H, true, true, false, true><<<gm, blk, 0, stream>>>(
        B_m, A_m, pWl_e2m, pWr_e2m, bl_e2m, B_m, N_M);
    mfma_gemm<H, H, true, true, false, true><<<ge, blk, 0, stream>>>(
        B_e, A_e, pWl_m2e, pWr_m2e, bl_m2e, B_e, N_E);

    // 5) ffw + relu: B -> A
    mfma_gemm<H, H, false, true, false, true><<<gm, blk, 0, stream>>>(
        B_m, nullptr, pWffw_m, nullptr, bffw_m, A_m, N_M);
    mfma_gemm<H, H, false, true, false, true><<<ge, blk, 0, stream>>>(
        B_e, nullptr, pWffw_e, nullptr, bffw_e, A_e, N_E);

    // 6) output projection: A -> B   (h_m in B_m, h_e in B_e)
    mfma_gemm<H, H, false, false, false, true><<<gm, blk, 0, stream>>>(
        A_m, nullptr, pWproj_m, nullptr, bproj_m, B_m, N_M);
    mfma_gemm<H, H, false, false, false, true><<<ge, blk, 0, stream>>>(
        A_e, nullptr, pWproj_e, nullptr, bproj_e, B_e, N_E);

    // 7) decoder m2e: U precompute (A region now dead) + edge decode
    dim3 gdq((NQ * 16 + 255) / 256);
    mfma_gemm<H, 256, false, false, false, false><<<gm, blk, 0, stream>>>(
        B_m, nullptr, pW1a_m2e, nullptr, nullptr, Us, N_M);
    mfma_gemm<H, 256, false, false, false, false><<<ge, blk, 0, stream>>>(
        B_e, nullptr, pW1b_m2e, nullptr, nullptr, Ud, N_E);
    edge_decode_kernel<<<gdq, blk, 0, stream>>>(
        Us, Ud, lsrc_m2e, ldst_m2e, bmlp_m2e, Wout_m2e, bout_m2e, out);

    // 8) decoder e2m
    mfma_gemm<H, 256, false, false, false, false><<<ge, blk, 0, stream>>>(
        B_e, nullptr, pW1a_e2m, nullptr, nullptr, Us, N_E);
    mfma_gemm<H, 256, false, false, false, false><<<gm, blk, 0, stream>>>(
        B_m, nullptr, pW1b_e2m, nullptr, nullptr, Ud, N_M);
    edge_decode_kernel<<<gdq, blk, 0, stream>>>(
        Us, Ud, lsrc_e2m, ldst_e2m, bmlp_e2m, Wout_e2m, bout_e2m, out + NLBL);
}

// Round 4
// 638.907 us; speedup vs baseline: 9.0523x; 1.0870x over previous
//
#include <hip/hip_runtime.h>
#include <math.h>

#define N_M 100000
#define N_E 50000
#define FM 256
#define FE 64
#define H 128
#define NEDGE 1000000
#define NLBL 250000

typedef unsigned short u16;
typedef short bf16x8 __attribute__((ext_vector_type(8)));
typedef float f32x4  __attribute__((ext_vector_type(4)));
typedef u16 u16x8    __attribute__((ext_vector_type(8)));
typedef u16 u16x4    __attribute__((ext_vector_type(4)));

__device__ __forceinline__ u16 f2bf(float x) {
    unsigned u = __float_as_uint(x);
    u += 0x7FFF + ((u >> 16) & 1);           // RNE
    return (u16)(u >> 16);
}
__device__ __forceinline__ float bf2f(u16 h) {
    return __uint_as_float(((unsigned)h) << 16);
}

// ---------------------------------------------------------------------------
// Weight packing into mfma_f32_16x16x32_bf16 B-fragment order.
// For tile (kt,nt): lane l, j  ->  W[kt*32 + (l>>4)*8 + j][nt*16 + (l&15)]
// Packed at: ((tile)*64 + l)*8 + j   (16B contiguous per lane)
// ---------------------------------------------------------------------------
#define NPACK 14
struct PackDesc { const float* src; u16* dst; int K, N; };
struct PackArgs { PackDesc d[NPACK]; };

__global__ __launch_bounds__(64)
void pack_kernel(PackArgs args)
{
    PackDesc pd = args.d[blockIdx.y];
    int KT = pd.K / 32, NT = pd.N / 16;
    int tile = blockIdx.x;
    if (tile >= KT * NT) return;
    int kt = tile / NT, nt = tile % NT;
    int l = threadIdx.x;
    u16* dst = pd.dst + ((size_t)tile * 64 + l) * 8;
    #pragma unroll
    for (int j = 0; j < 8; ++j) {
        float v = pd.src[(size_t)(kt * 32 + (l >> 4) * 8 + j) * pd.N + nt * 16 + (l & 15)];
        dst[j] = f2bf(v);
    }
}

// ---------------------------------------------------------------------------
// MFMA GEMM: C[M,N](bf16) = act( A1@W1 [+ A2@W2] [+ bias] )
// Block = 256 thr = 4 waves; each wave: 16 rows x N cols. No LDS.
// ---------------------------------------------------------------------------
template<int K, int N, bool HAS_A2, bool RELU, bool A_FP32, bool HAS_BIAS>
__global__ __launch_bounds__(256)
void mfma_gemm(const void* __restrict__ A1, const void* __restrict__ A2,
               const u16* __restrict__ W1p, const u16* __restrict__ W2p,
               const float* __restrict__ bias, u16* __restrict__ C, int M)
{
    constexpr int NT = N / 16, KT = K / 32;
    const int wid = threadIdx.x >> 6, lane = threadIdx.x & 63;
    const int row0 = blockIdx.x * 64 + wid * 16;
    if (row0 >= M) return;
    const int l15 = lane & 15, l4 = lane >> 4;

    f32x4 acc[NT];
    #pragma unroll
    for (int nt = 0; nt < NT; ++nt) acc[nt] = (f32x4){0.f, 0.f, 0.f, 0.f};

    const int npass = HAS_A2 ? 2 : 1;
    for (int pass = 0; pass < npass; ++pass) {
        const void* A = pass ? A2 : A1;
        const u16* Wp = pass ? W2p : W1p;
        #pragma unroll
        for (int kt = 0; kt < KT; ++kt) {
            bf16x8 a;
            if constexpr (A_FP32) {
                const float* ap = (const float*)A + (size_t)(row0 + l15) * K + kt * 32 + l4 * 8;
                float4 f0 = *(const float4*)ap;
                float4 f1 = *(const float4*)(ap + 4);
                a[0] = (short)f2bf(f0.x); a[1] = (short)f2bf(f0.y);
                a[2] = (short)f2bf(f0.z); a[3] = (short)f2bf(f0.w);
                a[4] = (short)f2bf(f1.x); a[5] = (short)f2bf(f1.y);
                a[6] = (short)f2bf(f1.z); a[7] = (short)f2bf(f1.w);
            } else {
                a = *(const bf16x8*)((const u16*)A + (size_t)(row0 + l15) * K + kt * 32 + l4 * 8);
            }
            #pragma unroll
            for (int nt = 0; nt < NT; ++nt) {
                bf16x8 b = *(const bf16x8*)(Wp + ((size_t)(kt * NT + nt) * 64 + lane) * 8);
                acc[nt] = __builtin_amdgcn_mfma_f32_16x16x32_bf16(a, b, acc[nt], 0, 0, 0);
            }
        }
    }

    #pragma unroll
    for (int nt = 0; nt < NT; ++nt) {
        #pragma unroll
        for (int r = 0; r < 4; ++r) {
            int row = row0 + l4 * 4 + r;
            int col = nt * 16 + l15;
            float v = acc[nt][r];
            if (HAS_BIAS) v += bias[col];
            if (RELU) v = fmaxf(v, 0.f);
            C[(size_t)row * N + col] = f2bf(v);
        }
    }
}

// ---------------------------------------------------------------------------
// CSR construction, XCD-partitioned: part = blockIdx.x & 7 owns dst range
// [part*range/8, (part+1)*range/8). Counter/cursor/CSR lines for a part are
// touched (almost) only by blocks on one XCD (round-robin dispatch), so the
// random 4B traffic stays in that XCD's L2 instead of ping-ponging.
// Correctness does NOT depend on the block->XCD mapping.
// ---------------------------------------------------------------------------
#define NSLICE 128
#define NBLKP (NSLICE * 8)

__global__ __launch_bounds__(256)
void hist_part_kernel(const int* __restrict__ dst_e2m,
                      const int* __restrict__ dst_m2e,
                      int* __restrict__ cnt_m, int* __restrict__ cnt_e)
{
    const int part  = blockIdx.x & 7;
    const int slice = blockIdx.x >> 3;
    const int dir   = blockIdx.y;
    const int* __restrict__ dstv = dir ? dst_m2e : dst_e2m;
    int* __restrict__ cnt        = dir ? cnt_e   : cnt_m;
    const int span = dir ? (N_E / 8) : (N_M / 8);
    const int lo = part * span, hi = lo + span;
    const int e0 = (int)((long long)slice * NEDGE / NSLICE);
    const int e1 = (int)((long long)(slice + 1) * NEDGE / NSLICE);
    for (int e = e0 + threadIdx.x; e < e1; e += 256) {
        int d = dstv[e];
        if (d >= lo && d < hi) atomicAdd(&cnt[d], 1);
    }
}

__global__ __launch_bounds__(256)
void fill_part_kernel(const int* __restrict__ src_e2m, const int* __restrict__ dst_e2m,
                      const int* __restrict__ src_m2e, const int* __restrict__ dst_m2e,
                      int* __restrict__ cur_m, int* __restrict__ cur_e,
                      int* __restrict__ csr_m, int* __restrict__ csr_e)
{
    const int part  = blockIdx.x & 7;
    const int slice = blockIdx.x >> 3;
    const int dir   = blockIdx.y;
    const int* __restrict__ srcv = dir ? src_m2e : src_e2m;
    const int* __restrict__ dstv = dir ? dst_m2e : dst_e2m;
    int* __restrict__ cur        = dir ? cur_e   : cur_m;
    int* __restrict__ csr        = dir ? csr_e   : csr_m;
    const int span = dir ? (N_E / 8) : (N_M / 8);
    const int lo = part * span, hi = lo + span;
    const int e0 = (int)((long long)slice * NEDGE / NSLICE);
    const int e1 = (int)((long long)(slice + 1) * NEDGE / NSLICE);
    for (int e = e0 + threadIdx.x; e < e1; e += 256) {
        int d = dstv[e];
        if (d >= lo && d < hi) {
            int p = atomicAdd(&cur[d], 1);
            csr[p] = srcv[e];
        }
    }
}

// ---------------------------------------------------------------------------
// Scan (exclusive prefix over counts) — unchanged.
// ---------------------------------------------------------------------------
__global__ __launch_bounds__(256)
void scan_local_kernel(const int* __restrict__ in, int* __restrict__ out,
                       int* __restrict__ partials, int n)
{
    __shared__ int ts[256];
    const int tid = threadIdx.x;
    int i0 = blockIdx.x * 4096 + tid * 16;
    int vals[16];
    int tsum = 0;
    #pragma unroll
    for (int i = 0; i < 16; ++i) {
        int idx = i0 + i;
        int v = (idx < n) ? in[idx] : 0;
        vals[i] = tsum;
        tsum += v;
    }
    ts[tid] = tsum;
    __syncthreads();
    for (int off = 1; off < 256; off <<= 1) {
        int v = (tid >= off) ? ts[tid - off] : 0;
        __syncthreads();
        ts[tid] += v;
        __syncthreads();
    }
    int texcl = ts[tid] - tsum;
    #pragma unroll
    for (int i = 0; i < 16; ++i) {
        int idx = i0 + i;
        if (idx < n) out[idx] = texcl + vals[i];
    }
    if (tid == 255) partials[blockIdx.x] = ts[255];
}

__global__ void scan_partials_kernel(int* partials, int np)
{
    if (threadIdx.x == 0) {
        int s = 0;
        for (int i = 0; i < np; ++i) { int v = partials[i]; partials[i] = s; s += v; }
    }
}

__global__ __launch_bounds__(256)
void scan_add_kernel(int* __restrict__ off, const int* __restrict__ partials,
                     int* __restrict__ cur, int n, int total)
{
    int idx = blockIdx.x * 256 + threadIdx.x;
    if (idx < n) {
        int v = off[idx] + partials[idx >> 12];
        off[idx] = v;
        cur[idx] = v;
    } else if (idx == n) {
        off[n] = total;
    }
}

// ---------------------------------------------------------------------------
// Gather-based segment mean on bf16: 32 lanes per dst node, 4 ch/lane.
// ---------------------------------------------------------------------------
__global__ __launch_bounds__(256)
void gather_mean_kernel(const u16* __restrict__ z,
                        const int* __restrict__ csr, const int* __restrict__ off,
                        u16* __restrict__ outm, int n)
{
    int g = (blockIdx.x * 256 + threadIdx.x) >> 5;
    if (g >= n) return;
    int lane = threadIdx.x & 31;
    int a = off[g], b = off[g + 1];
    float s0 = 0.f, s1 = 0.f, s2 = 0.f, s3 = 0.f;
    for (int e = a; e < b; ++e) {
        const u16x4 v = *(const u16x4*)&z[(size_t)csr[e] * H + lane * 4];
        s0 += bf2f(v[0]); s1 += bf2f(v[1]); s2 += bf2f(v[2]); s3 += bf2f(v[3]);
    }
    float inv = 1.0f / fmaxf((float)(b - a), 1.0f);
    u16x4 o;
    o[0] = f2bf(s0 * inv); o[1] = f2bf(s1 * inv);
    o[2] = f2bf(s2 * inv); o[3] = f2bf(s3 * inv);
    *(u16x4*)&outm[(size_t)g * H + lane * 4] = o;
}

// ---------------------------------------------------------------------------
// Edge decode: out[e] = sigmoid( relu(Us[s] + Ud[d] + b1) . W2 + b2 )
// 16 lanes per edge (16 ch each); each quarter-wave handles EPQ edges.
// ---------------------------------------------------------------------------
#define EPQ 8
#define NQ  31250   // NLBL / EPQ

__global__ __launch_bounds__(256)
void edge_decode_kernel(const u16* __restrict__ Us, const u16* __restrict__ Ud,
                        const int* __restrict__ lsrc, const int* __restrict__ ldst,
                        const float* __restrict__ b1, const float* __restrict__ W2,
                        const float* __restrict__ b2, float* __restrict__ out)
{
    const int t  = blockIdx.x * 256 + threadIdx.x;
    const int q  = t >> 4;
    const int li = t & 15;
    if (q >= NQ) return;

    float w2v[16], b1v[16];
    #pragma unroll
    for (int j = 0; j < 4; ++j) {
        float4 w = *(const float4*)&W2[li * 16 + j * 4];
        float4 bb = *(const float4*)&b1[li * 16 + j * 4];
        w2v[j*4+0] = w.x; w2v[j*4+1] = w.y; w2v[j*4+2] = w.z; w2v[j*4+3] = w.w;
        b1v[j*4+0] = bb.x; b1v[j*4+1] = bb.y; b1v[j*4+2] = bb.z; b1v[j*4+3] = bb.w;
    }
    const float bout = b2[0];

    #pragma unroll
    for (int i = 0; i < EPQ; ++i) {
        int e = q + i * NQ;
        int s = lsrc[e], d = ldst[e];
        const u16* us = Us + (size_t)s * 256 + li * 16;
        const u16* ud = Ud + (size_t)d * 256 + li * 16;
        u16x8 sa = *(const u16x8*)us;
        u16x8 sb = *(const u16x8*)(us + 8);
        u16x8 da = *(const u16x8*)ud;
        u16x8 db = *(const u16x8*)(ud + 8);
        float acc = 0.f;
        #pragma unroll
        for (int j = 0; j < 8; ++j)
            acc += fmaxf(bf2f(sa[j]) + bf2f(da[j]) + b1v[j], 0.f) * w2v[j];
        #pragma unroll
        for (int j = 0; j < 8; ++j)
            acc += fmaxf(bf2f(sb[j]) + bf2f(db[j]) + b1v[8 + j], 0.f) * w2v[8 + j];
        acc += __shfl_xor(acc, 1, 16);
        acc += __shfl_xor(acc, 2, 16);
        acc += __shfl_xor(acc, 4, 16);
        acc += __shfl_xor(acc, 8, 16);
        if (li == 0) out[e] = 1.0f / (1.0f + expf(-(acc + bout)));
    }
}

// ---------------------------------------------------------------------------
extern "C" void kernel_launch(void* const* d_in, const int* in_sizes, int n_in,
                              void* d_out, int out_size, void* d_ws, size_t ws_size,
                              hipStream_t stream)
{
    const float* x_m      = (const float*)d_in[0];
    const float* x_e      = (const float*)d_in[1];
    const int*   src_m2e  = (const int*)d_in[2];
    const int*   dst_m2e  = (const int*)d_in[3];
    const int*   src_e2m  = (const int*)d_in[4];
    const int*   dst_e2m  = (const int*)d_in[5];
    const int*   lsrc_m2e = (const int*)d_in[6];
    const int*   ldst_m2e = (const int*)d_in[7];
    const int*   lsrc_e2m = (const int*)d_in[8];
    const int*   ldst_e2m = (const int*)d_in[9];
    const float* Wp_m   = (const float*)d_in[10];
    const float* bp_m   = (const float*)d_in[11];
    const float* Wp_e   = (const float*)d_in[12];
    const float* bp_e   = (const float*)d_in[13];
    const float* Wl_m2e = (const float*)d_in[14];
    const float* bl_m2e = (const float*)d_in[15];
    const float* Wr_m2e = (const float*)d_in[16];
    const float* Wl_e2m = (const float*)d_in[17];
    const float* bl_e2m = (const float*)d_in[18];
    const float* Wr_e2m = (const float*)d_in[19];
    const float* Wffw_m = (const float*)d_in[20];
    const float* bffw_m = (const float*)d_in[21];
    const float* Wffw_e = (const float*)d_in[22];
    const float* bffw_e = (const float*)d_in[23];
    const float* Wproj_m = (const float*)d_in[24];
    const float* bproj_m = (const float*)d_in[25];
    const float* Wproj_e = (const float*)d_in[26];
    const float* bproj_e = (const float*)d_in[27];
    const float* Wmlp_m2e = (const float*)d_in[28];
    const float* bmlp_m2e = (const float*)d_in[29];
    const float* Wout_m2e = (const float*)d_in[30];
    const float* bout_m2e = (const float*)d_in[31];
    const float* Wmlp_e2m = (const float*)d_in[32];
    const float* bmlp_e2m = (const float*)d_in[33];
    const float* Wout_e2m = (const float*)d_in[34];
    const float* bout_e2m = (const float*)d_in[35];

    float* out = (float*)d_out;

    // ---- workspace layout (bf16 elems unless noted) ----
    u16* B_m = (u16*)d_ws;                       // mean_m -> h_m
    u16* B_e = B_m + (size_t)N_M * H;            // mean_e -> h_e
    u16* U0  = B_e + (size_t)N_E * H;
    u16* A_m = U0;                               // z_m -> h_ffw_m (dead after proj)
    u16* A_e = A_m + (size_t)N_M * H;
    u16* Us  = U0;
    u16* Ud  = U0 + (size_t)N_M * 256;
    int* ip    = (int*)(U0 + 2 * (size_t)N_M * 256);
    int* cnt_m = ip;                 ip += N_M;
    int* cnt_e = ip;                 ip += N_E;
    int* off_m = ip;                 ip += N_M + 1;
    int* off_e = ip;                 ip += N_E + 1;
    int* cur_m = ip;                 ip += N_M;
    int* cur_e = ip;                 ip += N_E;
    int* par_m = ip;                 ip += 32;
    int* par_e = ip;                 ip += 32;
    int* csr_m = ip;                 ip += NEDGE;
    int* csr_e = ip;                 ip += NEDGE;
    u16* pk = (u16*)(((uintptr_t)ip + 15) & ~(uintptr_t)15);
    u16* pWp_m   = pk;  pk += 256 * 128;
    u16* pWp_e   = pk;  pk += 64 * 128;
    u16* pWl_e2m = pk;  pk += 128 * 128;
    u16* pWr_e2m = pk;  pk += 128 * 128;
    u16* pWl_m2e = pk;  pk += 128 * 128;
    u16* pWr_m2e = pk;  pk += 128 * 128;
    u16* pWffw_m = pk;  pk += 128 * 128;
    u16* pWffw_e = pk;  pk += 128 * 128;
    u16* pWproj_m= pk;  pk += 128 * 128;
    u16* pWproj_e= pk;  pk += 128 * 128;
    u16* pW1a_m2e= pk;  pk += 128 * 256;
    u16* pW1b_m2e= pk;  pk += 128 * 256;
    u16* pW1a_e2m= pk;  pk += 128 * 256;
    u16* pW1b_e2m= pk;  pk += 128 * 256;

    dim3 blk(256);
    dim3 gm((N_M + 63) / 64), ge((N_E + 63) / 64);

    // 0) pack all weights into MFMA B-frag layout
    PackArgs pa;
    pa.d[0]  = { Wp_m,               pWp_m,    FM, H };
    pa.d[1]  = { Wp_e,               pWp_e,    FE, H };
    pa.d[2]  = { Wl_e2m,             pWl_e2m,  H,  H };
    pa.d[3]  = { Wr_e2m,             pWr_e2m,  H,  H };
    pa.d[4]  = { Wl_m2e,             pWl_m2e,  H,  H };
    pa.d[5]  = { Wr_m2e,             pWr_m2e,  H,  H };
    pa.d[6]  = { Wffw_m,             pWffw_m,  H,  H };
    pa.d[7]  = { Wffw_e,             pWffw_e,  H,  H };
    pa.d[8]  = { Wproj_m,            pWproj_m, H,  H };
    pa.d[9]  = { Wproj_e,            pWproj_e, H,  H };
    pa.d[10] = { Wmlp_m2e,           pW1a_m2e, H,  256 };
    pa.d[11] = { Wmlp_m2e + 128*256, pW1b_m2e, H,  256 };
    pa.d[12] = { Wmlp_e2m,           pW1a_e2m, H,  256 };
    pa.d[13] = { Wmlp_e2m + 128*256, pW1b_e2m, H,  256 };
    pack_kernel<<<dim3(64, NPACK), dim3(64), 0, stream>>>(pa);

    // 1) input projections (fp32 A -> bf16 out)
    mfma_gemm<FM, H, false, false, true, true><<<gm, blk, 0, stream>>>(
        x_m, nullptr, pWp_m, nullptr, bp_m, A_m, N_M);
    mfma_gemm<FE, H, false, false, true, true><<<ge, blk, 0, stream>>>(
        x_e, nullptr, pWp_e, nullptr, bp_e, A_e, N_E);

    // 2) CSR build (XCD-partitioned counting sort)
    hipMemsetAsync(cnt_m, 0, sizeof(int) * (N_M + N_E), stream);
    hist_part_kernel<<<dim3(NBLKP, 2), blk, 0, stream>>>(dst_e2m, dst_m2e, cnt_m, cnt_e);
    const int nb_m = (N_M + 4095) / 4096;
    const int nb_e = (N_E + 4095) / 4096;
    scan_local_kernel<<<dim3(nb_m), blk, 0, stream>>>(cnt_m, off_m, par_m, N_M);
    scan_local_kernel<<<dim3(nb_e), blk, 0, stream>>>(cnt_e, off_e, par_e, N_E);
    scan_partials_kernel<<<dim3(1), dim3(64), 0, stream>>>(par_m, nb_m);
    scan_partials_kernel<<<dim3(1), dim3(64), 0, stream>>>(par_e, nb_e);
    scan_add_kernel<<<dim3((N_M + 256) / 256 + 1), blk, 0, stream>>>(off_m, par_m, cur_m, N_M, NEDGE);
    scan_add_kernel<<<dim3((N_E + 256) / 256 + 1), blk, 0, stream>>>(off_e, par_e, cur_e, N_E, NEDGE);
    fill_part_kernel<<<dim3(NBLKP, 2), blk, 0, stream>>>(
        src_e2m, dst_e2m, src_m2e, dst_m2e, cur_m, cur_e, csr_m, csr_e);

    // 3) gather segment mean (bf16)
    gather_mean_kernel<<<dim3((N_M * 32 + 255) / 256), blk, 0, stream>>>(
        A_e, csr_m, off_m, B_m, N_M);
    gather_mean_kernel<<<dim3((N_E * 32 + 255) / 256), blk, 0, stream>>>(
        A_m, csr_e, off_e, B_e, N_E);

    // 4) SAGE combine + relu (in place on B)
    mfma_gemm<H, H, true, true, false, true><<<gm, blk, 0, stream>>>(
        B_m, A_m, pWl_e2m, pWr_e2m, bl_e2m, B_m, N_M);
    mfma_gemm<H, H, true, true, false, true><<<ge, blk, 0, stream>>>(
        B_e, A_e, pWl_m2e, pWr_m2e, bl_m2e, B_e, N_E);

    // 5) ffw + relu: B -> A
    mfma_gemm<H, H, false, true, false, true><<<gm, blk, 0, stream>>>(
        B_m, nullptr, pWffw_m, nullptr, bffw_m, A_m, N_M);
    mfma_gemm<H, H, false, true, false, true><<<ge, blk, 0, stream>>>(
        B_e, nullptr, pWffw_e, nullptr, bffw_e, A_e, N_E);

    // 6) output projection: A -> B   (h_m in B_m, h_e in B_e)
    mfma_gemm<H, H, false, false, false, true><<<gm, blk, 0, stream>>>(
        A_m, nullptr, pWproj_m, nullptr, bproj_m, B_m, N_M);
    mfma_gemm<H, H, false, false, false, true><<<ge, blk, 0, stream>>>(
        A_e, nullptr, pWproj_e, nullptr, bproj_e, B_e, N_E);

    // 7) decoder m2e: U precompute (A region now dead) + edge decode
    dim3 gdq((NQ * 16 + 255) / 256);
    mfma_gemm<H, 256, false, false, false, false><<<gm, blk, 0, stream>>>(
        B_m, nullptr, pW1a_m2e, nullptr, nullptr, Us, N_M);
    mfma_gemm<H, 256, false, false, false, false><<<ge, blk, 0, stream>>>(
        B_e, nullptr, pW1b_m2e, nullptr, nullptr, Ud, N_E);
    edge_decode_kernel<<<gdq, blk, 0, stream>>>(
        Us, Ud, lsrc_m2e, ldst_m2e, bmlp_m2e, Wout_m2e, bout_m2e, out);

    // 8) decoder e2m
    mfma_gemm<H, 256, false, false, false, false><<<ge, blk, 0, stream>>>(
        B_e, nullptr, pW1a_e2m, nullptr, nullptr, Us, N_E);
    mfma_gemm<H, 256, false, false, false, false><<<gm, blk, 0, stream>>>(
        B_m, nullptr, pW1b_e2m, nullptr, nullptr, Ud, N_M);
    edge_decode_kernel<<<gdq, blk, 0, stream>>>(
        Us, Ud, lsrc_e2m, ldst_e2m, bmlp_e2m, Wout_e2m, bout_e2m, out + NLBL);
}